// Round 4
// baseline (197.998 us; speedup 1.0000x reference)
//
#include <hip/hip_runtime.h>

typedef __bf16 bf16;
typedef __bf16 bf16x8 __attribute__((ext_vector_type(8)));
typedef __bf16 bf16x4 __attribute__((ext_vector_type(4)));
typedef float  f32x4  __attribute__((ext_vector_type(4)));
typedef unsigned u32x2 __attribute__((ext_vector_type(2)));

typedef __attribute__((address_space(1))) const void GASV;
typedef __attribute__((address_space(3))) void LASV;

__device__ __forceinline__ void gload16(const void* g, void* l) {
  __builtin_amdgcn_global_load_lds((GASV*)g, (LASV*)l, 16, 0, 0);
}

// ---------------- all four weight transposes fp32->bf16 in one launch ----------------
__global__ __launch_bounds__(256) void wconv_all(const float* __restrict__ qkv_w,
                                                 const float* __restrict__ proj_w,
                                                 const float* __restrict__ w1,
                                                 const float* __restrict__ w2,
                                                 bf16* __restrict__ Wtqkv,
                                                 bf16* __restrict__ WtP,
                                                 bf16* __restrict__ Wt1,
                                                 bf16* __restrict__ Wt2) {
  const int idx = blockIdx.x * 256 + threadIdx.x;   // 524288 total
  if (idx < 196608) {
    const int k = idx & 255, n = idx >> 8;
    Wtqkv[idx] = (bf16)qkv_w[k * 768 + n];
  } else if (idx < 262144) {
    const int i = idx - 196608, k = i & 255, n = i >> 8;
    WtP[i] = (bf16)proj_w[k * 256 + n];
  } else if (idx < 393216) {
    const int i = idx - 262144, k = i & 255, n = i >> 8;
    Wt1[i] = (bf16)w1[k * 512 + n];
  } else {
    const int i = idx - 393216, k = i & 511, n = i >> 9;
    Wt2[i] = (bf16)w2[k * 256 + n];
  }
}

// ---------------- layernorm rows of 256 (fp32 in -> bf16 out); 1 wave per row ----------------
__global__ __launch_bounds__(256) void ln_fwd(const float* __restrict__ x,
                                              const float* __restrict__ gam,
                                              const float* __restrict__ bet,
                                              bf16* __restrict__ out) {
  const int lane = threadIdx.x & 63;
  const int w = threadIdx.x >> 6;
  const size_t row = (size_t)blockIdx.x * 4 + w;
  const float4 v = *(const float4*)(x + row * 256 + lane * 4);
  float s1 = v.x + v.y + v.z + v.w;
  float s2 = v.x * v.x + v.y * v.y + v.z * v.z + v.w * v.w;
#pragma unroll
  for (int m = 1; m < 64; m <<= 1) {
    s1 += __shfl_xor(s1, m);
    s2 += __shfl_xor(s2, m);
  }
  const float mu = s1 * (1.0f / 256.0f);
  const float var = s2 * (1.0f / 256.0f) - mu * mu;
  const float rs = rsqrtf(var + 1e-5f);
  const float4 g4 = *(const float4*)(gam + lane * 4);
  const float4 b4 = *(const float4*)(bet + lane * 4);
  bf16x4 o;
  o[0] = (bf16)((v.x - mu) * rs * g4.x + b4.x);
  o[1] = (bf16)((v.y - mu) * rs * g4.y + b4.y);
  o[2] = (bf16)((v.z - mu) * rs * g4.z + b4.z);
  o[3] = (bf16)((v.w - mu) * rs * g4.w + b4.w);
  *(bf16x4*)(out + row * 256 + lane * 4) = o;
}

// ---------------- BT-form GEMM: C[r][c] = sum_k A[r][k]*Bt[c][k]  (128x128 tile, BK=64) ----
template <int EPI>
__global__ __launch_bounds__(256) void gemm_bt(const bf16* __restrict__ A,
                                               const bf16* __restrict__ Bt,
                                               const float* __restrict__ bias,
                                               const float* __restrict__ res,
                                               void* __restrict__ outp,
                                               int M, int N, int K) {
  __shared__ bf16 Al[2][8192];
  __shared__ bf16 Bl[2][8192];
  const int tid = threadIdx.x;
  const int lane = tid & 63;
  const int wid = tid >> 6;
  const int wm = wid >> 1, wn = wid & 1;
  const int nbm = M >> 7;
  const int bm = (int)blockIdx.x % nbm;
  const int bn = (int)blockIdx.x / nbm;
  const int m0 = bm << 7, n0 = bn << 7;
  const int nk = K >> 6;

  f32x4 acc[4][4];
#pragma unroll
  for (int i = 0; i < 4; ++i)
#pragma unroll
    for (int j = 0; j < 4; ++j) acc[i][j] = (f32x4){0.f, 0.f, 0.f, 0.f};

  auto stage = [&](int t, int s) {
    const int k0 = t << 6;
#pragma unroll
    for (int p = 0; p < 4; ++p) {
      const int idx = p * 4096 + tid * 16;   // byte within 16KB tile
      const int row = idx >> 7;              // 128B per row (64 bf16)
      const int colb = idx & 127;
      gload16((const char*)(A + ((size_t)(m0 + row) * K + k0)) + colb,
              (char*)&Al[s][0] + p * 4096 + ((tid >> 6) << 10));
      gload16((const char*)(Bt + ((size_t)(n0 + row) * K + k0)) + colb,
              (char*)&Bl[s][0] + p * 4096 + ((tid >> 6) << 10));
    }
  };

  stage(0, 0);
  asm volatile("s_waitcnt vmcnt(0)" ::: "memory");
  __syncthreads();

  for (int t = 0; t < nk; ++t) {
    if (t + 1 < nk) stage(t + 1, (t + 1) & 1);  // prefetch flies during MFMA
    const bf16* pa = &Al[t & 1][0] + (wm * 64 + (lane & 15)) * 64 + ((lane >> 4) << 3);
    const bf16* pb = &Bl[t & 1][0] + (wn * 64 + (lane & 15)) * 64 + ((lane >> 4) << 3);
    bf16x8 av[4][2], bv[4][2];
#pragma unroll
    for (int f = 0; f < 4; ++f)
#pragma unroll
      for (int ks = 0; ks < 2; ++ks) {
        av[f][ks] = *(const bf16x8*)(pa + f * 1024 + ks * 32);
        bv[f][ks] = *(const bf16x8*)(pb + f * 1024 + ks * 32);
      }
    __builtin_amdgcn_s_setprio(1);
#pragma unroll
    for (int fm = 0; fm < 4; ++fm)
#pragma unroll
      for (int fn = 0; fn < 4; ++fn) {
        acc[fm][fn] = __builtin_amdgcn_mfma_f32_16x16x32_bf16(av[fm][0], bv[fn][0], acc[fm][fn], 0, 0, 0);
        acc[fm][fn] = __builtin_amdgcn_mfma_f32_16x16x32_bf16(av[fm][1], bv[fn][1], acc[fm][fn], 0, 0, 0);
      }
    __builtin_amdgcn_s_setprio(0);
    asm volatile("s_waitcnt vmcnt(0)" ::: "memory");
    __syncthreads();
  }

#pragma unroll
  for (int fm = 0; fm < 4; ++fm)
#pragma unroll
    for (int fn = 0; fn < 4; ++fn) {
      const int r0 = m0 + wm * 64 + fm * 16 + ((lane >> 4) << 2);
      const int c = n0 + wn * 64 + fn * 16 + (lane & 15);
#pragma unroll
      for (int j = 0; j < 4; ++j) {
        const int r = r0 + j;
        const float v = acc[fm][fn][j];
        if constexpr (EPI == 0) {
          ((bf16*)outp)[(size_t)r * N + c] = (bf16)(v + bias[c]);
        } else if constexpr (EPI == 1) {
          ((bf16*)outp)[(size_t)r * 2048 + ((size_t)(c >> 11)) * 524288 + (c & 2047)] =
              (bf16)(v + bias[r]);
        } else if constexpr (EPI == 2) {
          ((float*)outp)[(size_t)r * N + c] = v + bias[c] + res[(size_t)r * N + c];
        } else {
          const float u = v + bias[c];
          ((bf16*)outp)[(size_t)r * N + c] = (bf16)(u * 0.5f * (1.0f + erff(u * 0.70710678118f)));
        }
      }
    }
}

// ---------------- flash attention v4: 8 waves, kv-split pairs ------------------------------
// QBLK=128 (4 q-slices x 32 q), waves 0-3 = even kv tiles, waves 4-7 = odd kv tiles.
// Per group: double-buffered frag-major K/V LDS. End: partner-wave flash merge via LDS.
__global__ __launch_bounds__(512, 4) void attn_fwd(const bf16* __restrict__ qk,
                                                   const bf16* __restrict__ vT,
                                                   bf16* __restrict__ ob) {
  __shared__ bf16 Kl[2][2][4096];   // [grp][slot] 8KB tiles -> 32KB (reused for O merge)
  __shared__ bf16 Vl[2][2][4096];   // 32KB
  __shared__ bf16 Pl[8][1024];      // per-wave 2KB P slab (reused per ksl; stats in epilogue)
  const int tid = threadIdx.x;
  const int lane = tid & 63;
  const int w = tid >> 6;           // 0..7
  const int grp = w >> 2;           // kv parity group
  const int wq = w & 3;             // q slice
  const int g = lane >> 4;
  const int qi = lane & 15;
  const int bh = blockIdx.x & 31;   // same bh -> same XCD (mod-8 invariant)
  const int qt = blockIdx.x >> 5;   // 16 q-tiles of 128
  const int b = bh >> 2, h = bh & 3;

  // Q fragments f=0,1 (B-operand of S^T): col q = f*16+qi, k(d) = half*32 + g*8 + j
  const size_t qrow0 = (size_t)b * 2048 + qt * 128 + wq * 32 + qi;
  bf16x8 qf[2][2];
#pragma unroll
  for (int f = 0; f < 2; ++f) {
    const bf16* qp = qk + (qrow0 + f * 16) * 512 + h * 64 + g * 8;
    qf[f][0] = *(const bf16x8*)qp;
    qf[f][1] = *(const bf16x8*)(qp + 32);
  }

  float mrun[2] = {0.f, 0.f};
  float lsum[2] = {0.f, 0.f};
  f32x4 o[4][2];
#pragma unroll
  for (int i = 0; i < 4; ++i)
#pragma unroll
    for (int f = 0; f < 2; ++f) o[i][f] = (f32x4){0.f, 0.f, 0.f, 0.f};

  constexpr float CEXP = 0.125f * 1.44269504088896340736f;
  constexpr float THR = 8.0f / CEXP;

  // staging sources (frag-major pre-permute); group g starts at tile g, advances by 2 tiles
  const char* kbase = (const char*)qk + ((size_t)b * 2048) * 1024 + 512 + h * 128;
  const char* vbase = (const char*)vT + (size_t)bh * 262144;
  const char* ks[2];
  const char* vs[2];
#pragma unroll
  for (int i = 0; i < 2; ++i) {
    const int fk = i * 2 + (wq >> 1);
    const int half = wq & 1;
    ks[i] = kbase + (size_t)grp * 65536 + (fk * 16 + qi) * 1024 + half * 64 + g * 16;
    vs[i] = vbase + (size_t)grp * 128 + (size_t)(fk * 16 + qi) * 4096 + half * 64 + g * 16;
  }
  char* const kslab = (char*)&Kl[grp][0][0];
  char* const vslab = (char*)&Vl[grp][0][0];
  // P slab (2KB, private per wave)
  char* const pw = (char*)&Pl[w][0];
  int paddrb[2];
#pragma unroll
  for (int bb = 0; bb < 2; ++bb)
    paddrb[bb] = (bb * 2 + (g >> 1)) * 256 + qi * 16 + (g & 1) * 8;
  const char* const prd = pw + lane * 16;

  auto stage = [&](int slot) {
    char* kd = kslab + slot * 8192 + wq * 1024;
    char* vd = vslab + slot * 8192 + wq * 1024;
    gload16(ks[0], kd);
    gload16(ks[1], kd + 4096);
    gload16(vs[0], vd);
    gload16(vs[1], vd + 4096);
    ks[0] += 131072; ks[1] += 131072;   // +2 kv tiles
    vs[0] += 256;    vs[1] += 256;
  };

  stage(0);
  asm volatile("s_waitcnt vmcnt(0)" ::: "memory");
  __builtin_amdgcn_s_barrier();

  for (int t = 0; t < 16; ++t) {
    if (t < 15) stage((t + 1) & 1);
    // ---- S^T = K·Q^T : linear frag reads ----
    const char* kb = kslab + (t & 1) * 8192 + lane * 16;
    f32x4 st[4][2];
    __builtin_amdgcn_s_setprio(1);
#pragma unroll
    for (int fk = 0; fk < 4; ++fk) {
      const bf16x8 k0 = *(const bf16x8*)(kb + fk * 2048);
      const bf16x8 k1 = *(const bf16x8*)(kb + fk * 2048 + 1024);
#pragma unroll
      for (int f = 0; f < 2; ++f) {
        f32x4 z = (f32x4){0.f, 0.f, 0.f, 0.f};
        st[fk][f] = __builtin_amdgcn_mfma_f32_16x16x32_bf16(k0, qf[f][0], z, 0, 0, 0);
        st[fk][f] = __builtin_amdgcn_mfma_f32_16x16x32_bf16(k1, qf[f][1], st[fk][f], 0, 0, 0);
      }
    }
    __builtin_amdgcn_s_setprio(0);
    // ---- online softmax (lane-local col q = f*16+qi; kv slice = fk*16+g*4+j) ----
    float pmax[2];
#pragma unroll
    for (int f = 0; f < 2; ++f) {
      float m0 = fmaxf(fmaxf(st[0][f][0], st[0][f][1]), fmaxf(st[0][f][2], st[0][f][3]));
      float m1 = fmaxf(fmaxf(st[1][f][0], st[1][f][1]), fmaxf(st[1][f][2], st[1][f][3]));
      float m2 = fmaxf(fmaxf(st[2][f][0], st[2][f][1]), fmaxf(st[2][f][2], st[2][f][3]));
      float m3 = fmaxf(fmaxf(st[3][f][0], st[3][f][1]), fmaxf(st[3][f][2], st[3][f][3]));
      pmax[f] = fmaxf(fmaxf(m0, m1), fmaxf(m2, m3));
    }
    if (!__all(pmax[0] <= mrun[0] + THR && pmax[1] <= mrun[1] + THR)) {  // rare
#pragma unroll
      for (int f = 0; f < 2; ++f) {
        float mt = fmaxf(pmax[f], __shfl_xor(pmax[f], 16));
        mt = fmaxf(mt, __shfl_xor(mt, 32));
        const float mnew = fmaxf(mrun[f], mt);
        const float alpha = exp2f(CEXP * (mrun[f] - mnew));
        lsum[f] *= alpha;
#pragma unroll
        for (int fd = 0; fd < 4; ++fd)
#pragma unroll
          for (int j = 0; j < 4; ++j) o[fd][f][j] *= alpha;
        mrun[f] = mnew;
      }
    }
    unsigned pk[4][2][2];
#pragma unroll
    for (int f = 0; f < 2; ++f) {
      const float negcm = -CEXP * mrun[f];
      float ts = 0.f;
#pragma unroll
      for (int fk = 0; fk < 4; ++fk)
#pragma unroll
        for (int jp = 0; jp < 2; ++jp) {
          const float p0 = exp2f(fmaf(st[fk][f][2 * jp], CEXP, negcm));
          const float p1 = exp2f(fmaf(st[fk][f][2 * jp + 1], CEXP, negcm));
          ts += p0 + p1;
          union { bf16 h2[2]; unsigned u; } cv;
          cv.h2[0] = (bf16)p0;
          cv.h2[1] = (bf16)p1;
          pk[fk][f][jp] = cv.u;
        }
      lsum[f] += ts;
    }
    // ---- PV per ksl-half: P slab round-trip + V frag reads (all private/linear) ----
    const char* vb = vslab + (t & 1) * 8192 + lane * 16;
#pragma unroll
    for (int ksl = 0; ksl < 2; ++ksl) {
#pragma unroll
      for (int bb = 0; bb < 2; ++bb) {
        const int fk = 2 * ksl + bb;
#pragma unroll
        for (int f = 0; f < 2; ++f) {
          u32x2 pv2;
          pv2[0] = pk[fk][f][0];
          pv2[1] = pk[fk][f][1];
          *(u32x2*)(pw + f * 1024 + paddrb[bb]) = pv2;
        }
      }
      bf16x8 pa[2];
#pragma unroll
      for (int f = 0; f < 2; ++f) pa[f] = *(const bf16x8*)(prd + f * 1024);
      __builtin_amdgcn_s_setprio(1);
#pragma unroll
      for (int fd = 0; fd < 4; ++fd) {
        const bf16x8 vv = *(const bf16x8*)(vb + fd * 2048 + ksl * 1024);
#pragma unroll
        for (int f = 0; f < 2; ++f)
          o[fd][f] = __builtin_amdgcn_mfma_f32_16x16x32_bf16(vv, pa[f], o[fd][f], 0, 0, 0);
      }
      __builtin_amdgcn_s_setprio(0);
    }
    asm volatile("s_waitcnt vmcnt(0)" ::: "memory");
    __builtin_amdgcn_s_barrier();
  }

  // ---- partner-wave flash merge (grp0 <-> grp1, same q) ----
#pragma unroll
  for (int f = 0; f < 2; ++f) {
    float l = lsum[f];
    l += __shfl_xor(l, 16);
    l += __shfl_xor(l, 32);
    lsum[f] = l;
  }
  // stats: {m0,l0,m1,l1} per lane
  f32x4 stv;
  stv[0] = mrun[0]; stv[1] = lsum[0]; stv[2] = mrun[1]; stv[3] = lsum[1];
  *(f32x4*)((char*)&Pl[0][0] + w * 1024 + lane * 16) = stv;
  // O-half we do NOT keep: grp0 writes fd {2,3}, grp1 writes fd {0,1}
  char* const oslab = (char*)&Kl[0][0][0] + w * 4096;
#pragma unroll
  for (int fd2 = 0; fd2 < 2; ++fd2) {
    const int wf = grp ? fd2 : 2 + fd2;
#pragma unroll
    for (int f = 0; f < 2; ++f)
      *(f32x4*)(oslab + (fd2 * 2 + f) * 1024 + lane * 16) = o[wf][f];
  }
  __syncthreads();
  const int p = w ^ 4;
  const f32x4 pst = *(const f32x4*)((char*)&Pl[0][0] + p * 1024 + lane * 16);
  const char* const pslab = (char*)&Kl[0][0][0] + p * 4096;
#pragma unroll
  for (int f = 0; f < 2; ++f) {
    const float mme = mrun[f], lme = lsum[f];
    const float mot = pst[2 * f], lot = pst[2 * f + 1];
    const float ms = fmaxf(mme, mot);
    const float am = exp2f(CEXP * (mme - ms));
    const float ao = exp2f(CEXP * (mot - ms));
    const float inv = 1.0f / (lme * am + lot * ao);
#pragma unroll
    for (int fd2 = 0; fd2 < 2; ++fd2) {
      const int kf = grp ? 2 + fd2 : fd2;   // kept global fd
      const f32x4 po = *(const f32x4*)(pslab + (fd2 * 2 + f) * 1024 + lane * 16);
      bf16x4 ov;
#pragma unroll
      for (int j = 0; j < 4; ++j)
        ov[j] = (bf16)((o[kf][f][j] * am + po[j] * ao) * inv);
      *(bf16x4*)(ob + (qrow0 + f * 16) * 256 + h * 64 + kf * 16 + g * 4) = ov;
    }
  }
}

extern "C" void kernel_launch(void* const* d_in, const int* in_sizes, int n_in,
                              void* d_out, int out_size, void* d_ws, size_t ws_size,
                              hipStream_t stream) {
  const float* x      = (const float*)d_in[0];
  const float* qkv_w  = (const float*)d_in[1];
  const float* qkv_b  = (const float*)d_in[2];
  const float* proj_w = (const float*)d_in[3];
  const float* proj_b = (const float*)d_in[4];
  const float* ln1_g  = (const float*)d_in[5];
  const float* ln1_b  = (const float*)d_in[6];
  const float* ln2_g  = (const float*)d_in[7];
  const float* ln2_b  = (const float*)d_in[8];
  const float* mlp_w1 = (const float*)d_in[9];
  const float* mlp_b1 = (const float*)d_in[10];
  const float* mlp_w2 = (const float*)d_in[11];
  const float* mlp_b2 = (const float*)d_in[12];
  float* out = (float*)d_out;

  char* ws = (char*)d_ws;
  bf16* Wtqkv = (bf16*)(ws);              // [768][256]   393216 B
  bf16* WtP   = (bf16*)(ws + 393216);     // [256][256]   131072 B
  bf16* Wt1   = (bf16*)(ws + 524288);     // [512][256]   262144 B
  bf16* Wt2   = (bf16*)(ws + 786432);     // [256][512]   262144 B
  bf16* h     = (bf16*)(ws + 1048576);    // [16384][256] 8388608 B
  bf16* qkb   = (bf16*)(ws + 9437184);    // [16384][512] 16777216 B
  bf16* vT    = (bf16*)(ws + 26214400);   // [32][64][2048] 8388608 B
  bf16* obuf  = (bf16*)(ws + 34603008);   // [16384][256] 8388608 B
  float* x2   = (float*)(ws + 42991616);  // [16384][256] 16777216 B  (total 59.8 MB)
  bf16* a1 = qkb;  // reuse (qkb dead after attn)
  bf16* h2 = h;    // reuse (h dead after V gemm)

  wconv_all<<<2048, 256, 0, stream>>>(qkv_w, proj_w, mlp_w1, mlp_w2, Wtqkv, WtP, Wt1, Wt2);

  ln_fwd<<<4096, 256, 0, stream>>>(x, ln1_g, ln1_b, h);
  // Q,K: h @ W_qk  -> qkb [16384][512]
  gemm_bt<0><<<512, 256, 0, stream>>>(h, Wtqkv, qkv_b, nullptr, qkb, 16384, 512, 256);
  // V^T: Wv^T @ h^T -> vT [32][64][2048]  (swapped-operand GEMM, scatter epilogue)
  gemm_bt<1><<<256, 256, 0, stream>>>(Wtqkv + 512 * 256, h, qkv_b + 512, nullptr, vT, 256, 16384, 256);
  attn_fwd<<<512, 512, 0, stream>>>(qkb, vT, obuf);
  // proj + residual -> x2 (f32)
  gemm_bt<2><<<256, 256, 0, stream>>>(obuf, WtP, proj_b, x, x2, 16384, 256, 256);
  ln_fwd<<<4096, 256, 0, stream>>>(x2, ln2_g, ln2_b, h2);
  // fc1 + gelu -> a1 (bf16)
  gemm_bt<3><<<512, 256, 0, stream>>>(h2, Wt1, mlp_b1, nullptr, a1, 16384, 512, 256);
  // fc2 + residual -> out (f32)
  gemm_bt<2><<<256, 256, 0, stream>>>(a1, Wt2, mlp_b2, x2, out, 16384, 256, 512);
}

// Round 5
// 175.401 us; speedup vs baseline: 1.1288x; 1.1288x over previous
//
#include <hip/hip_runtime.h>

typedef __bf16 bf16;
typedef __bf16 bf16x8 __attribute__((ext_vector_type(8)));
typedef __bf16 bf16x4 __attribute__((ext_vector_type(4)));
typedef float  f32x4  __attribute__((ext_vector_type(4)));
typedef unsigned u32x2 __attribute__((ext_vector_type(2)));

typedef __attribute__((address_space(1))) const void GASV;
typedef __attribute__((address_space(3))) void LASV;

__device__ __forceinline__ void gload16(const void* g, void* l) {
  __builtin_amdgcn_global_load_lds((GASV*)g, (LASV*)l, 16, 0, 0);
}

constexpr float CEXP = 0.125f * 1.44269504088896340736f;  // attn scale folded into exp2

// ---------------- all four weight transposes fp32->bf16 in one launch ----------------
__global__ __launch_bounds__(256) void wconv_all(const float* __restrict__ qkv_w,
                                                 const float* __restrict__ proj_w,
                                                 const float* __restrict__ w1,
                                                 const float* __restrict__ w2,
                                                 bf16* __restrict__ Wtqkv,
                                                 bf16* __restrict__ WtP,
                                                 bf16* __restrict__ Wt1,
                                                 bf16* __restrict__ Wt2) {
  const int idx = blockIdx.x * 256 + threadIdx.x;   // 524288 total
  if (idx < 196608) {
    const int k = idx & 255, n = idx >> 8;
    Wtqkv[idx] = (bf16)qkv_w[k * 768 + n];
  } else if (idx < 262144) {
    const int i = idx - 196608, k = i & 255, n = i >> 8;
    WtP[i] = (bf16)proj_w[k * 256 + n];
  } else if (idx < 393216) {
    const int i = idx - 262144, k = i & 255, n = i >> 8;
    Wt1[i] = (bf16)w1[k * 512 + n];
  } else {
    const int i = idx - 393216, k = i & 511, n = i >> 9;
    Wt2[i] = (bf16)w2[k * 256 + n];
  }
}

// ---------------- layernorm rows of 256 (fp32 in -> bf16 out); 1 wave per row ----------------
__global__ __launch_bounds__(256) void ln_fwd(const float* __restrict__ x,
                                              const float* __restrict__ gam,
                                              const float* __restrict__ bet,
                                              bf16* __restrict__ out) {
  const int lane = threadIdx.x & 63;
  const int w = threadIdx.x >> 6;
  const size_t row = (size_t)blockIdx.x * 4 + w;
  const float4 v = *(const float4*)(x + row * 256 + lane * 4);
  float s1 = v.x + v.y + v.z + v.w;
  float s2 = v.x * v.x + v.y * v.y + v.z * v.z + v.w * v.w;
#pragma unroll
  for (int m = 1; m < 64; m <<= 1) {
    s1 += __shfl_xor(s1, m);
    s2 += __shfl_xor(s2, m);
  }
  const float mu = s1 * (1.0f / 256.0f);
  const float var = s2 * (1.0f / 256.0f) - mu * mu;
  const float rs = rsqrtf(var + 1e-5f);
  const float4 g4 = *(const float4*)(gam + lane * 4);
  const float4 b4 = *(const float4*)(bet + lane * 4);
  bf16x4 o;
  o[0] = (bf16)((v.x - mu) * rs * g4.x + b4.x);
  o[1] = (bf16)((v.y - mu) * rs * g4.y + b4.y);
  o[2] = (bf16)((v.z - mu) * rs * g4.z + b4.z);
  o[3] = (bf16)((v.w - mu) * rs * g4.w + b4.w);
  *(bf16x4*)(out + row * 256 + lane * 4) = o;
}

// ---------------- BT-form GEMM: C[r][c] = sum_k A[r][k]*Bt[c][k]  (128x128 tile, BK=64) ----
template <int EPI>
__global__ __launch_bounds__(256) void gemm_bt(const bf16* __restrict__ A,
                                               const bf16* __restrict__ Bt,
                                               const float* __restrict__ bias,
                                               const float* __restrict__ res,
                                               void* __restrict__ outp,
                                               int M, int N, int K) {
  __shared__ bf16 Al[2][8192];
  __shared__ bf16 Bl[2][8192];
  const int tid = threadIdx.x;
  const int lane = tid & 63;
  const int wid = tid >> 6;
  const int wm = wid >> 1, wn = wid & 1;
  const int nbm = M >> 7;
  const int bm = (int)blockIdx.x % nbm;
  const int bn = (int)blockIdx.x / nbm;
  const int m0 = bm << 7, n0 = bn << 7;
  const int nk = K >> 6;

  f32x4 acc[4][4];
#pragma unroll
  for (int i = 0; i < 4; ++i)
#pragma unroll
    for (int j = 0; j < 4; ++j) acc[i][j] = (f32x4){0.f, 0.f, 0.f, 0.f};

  auto stage = [&](int t, int s) {
    const int k0 = t << 6;
#pragma unroll
    for (int p = 0; p < 4; ++p) {
      const int idx = p * 4096 + tid * 16;   // byte within 16KB tile
      const int row = idx >> 7;              // 128B per row (64 bf16)
      const int colb = idx & 127;
      gload16((const char*)(A + ((size_t)(m0 + row) * K + k0)) + colb,
              (char*)&Al[s][0] + p * 4096 + ((tid >> 6) << 10));
      gload16((const char*)(Bt + ((size_t)(n0 + row) * K + k0)) + colb,
              (char*)&Bl[s][0] + p * 4096 + ((tid >> 6) << 10));
    }
  };

  stage(0, 0);
  asm volatile("s_waitcnt vmcnt(0)" ::: "memory");
  __syncthreads();

  for (int t = 0; t < nk; ++t) {
    if (t + 1 < nk) stage(t + 1, (t + 1) & 1);  // prefetch flies during MFMA
    const bf16* pa = &Al[t & 1][0] + (wm * 64 + (lane & 15)) * 64 + ((lane >> 4) << 3);
    const bf16* pb = &Bl[t & 1][0] + (wn * 64 + (lane & 15)) * 64 + ((lane >> 4) << 3);
    bf16x8 av[4][2], bv[4][2];
#pragma unroll
    for (int f = 0; f < 4; ++f)
#pragma unroll
      for (int ks = 0; ks < 2; ++ks) {
        av[f][ks] = *(const bf16x8*)(pa + f * 1024 + ks * 32);
        bv[f][ks] = *(const bf16x8*)(pb + f * 1024 + ks * 32);
      }
    __builtin_amdgcn_s_setprio(1);
#pragma unroll
    for (int fm = 0; fm < 4; ++fm)
#pragma unroll
      for (int fn = 0; fn < 4; ++fn) {
        acc[fm][fn] = __builtin_amdgcn_mfma_f32_16x16x32_bf16(av[fm][0], bv[fn][0], acc[fm][fn], 0, 0, 0);
        acc[fm][fn] = __builtin_amdgcn_mfma_f32_16x16x32_bf16(av[fm][1], bv[fn][1], acc[fm][fn], 0, 0, 0);
      }
    __builtin_amdgcn_s_setprio(0);
    asm volatile("s_waitcnt vmcnt(0)" ::: "memory");
    __syncthreads();
  }

#pragma unroll
  for (int fm = 0; fm < 4; ++fm)
#pragma unroll
    for (int fn = 0; fn < 4; ++fn) {
      const int r0 = m0 + wm * 64 + fm * 16 + ((lane >> 4) << 2);
      const int c = n0 + wn * 64 + fn * 16 + (lane & 15);
#pragma unroll
      for (int j = 0; j < 4; ++j) {
        const int r = r0 + j;
        const float v = acc[fm][fn][j];
        if constexpr (EPI == 0) {
          ((bf16*)outp)[(size_t)r * N + c] = (bf16)(v + bias[c]);
        } else if constexpr (EPI == 1) {
          ((bf16*)outp)[(size_t)r * 2048 + ((size_t)(c >> 11)) * 524288 + (c & 2047)] =
              (bf16)(v + bias[r]);
        } else if constexpr (EPI == 2) {
          ((float*)outp)[(size_t)r * N + c] = v + bias[c] + res[(size_t)r * N + c];
        } else {
          const float u = v + bias[c];
          ((bf16*)outp)[(size_t)r * N + c] = (bf16)(u * 0.5f * (1.0f + erff(u * 0.70710678118f)));
        }
      }
    }
}

// ---------------- flash attention v5: block-level kv-split ---------------------------------
// 1024 blocks = 32 bh x 16 qt x 2 kv-halves; 256 thr (4 waves x 32 q), KVBLK=64, 16 iters.
// Double-buffered frag-major K/V LDS (40KB -> 4 blocks/CU = 4 waves/SIMD). Each block writes
// unnormalized bf16 partial-O + f32 (m,l); attn_merge does the exact flash merge.
__global__ __launch_bounds__(256) void attn_fwd(const bf16* __restrict__ qk,
                                                const bf16* __restrict__ vT,
                                                bf16* __restrict__ po,
                                                float* __restrict__ pstats) {
  __shared__ bf16 Kl[2][4096];   // 8KB frag-major K tile per slot
  __shared__ bf16 Vl[2][4096];
  __shared__ bf16 Pl[4][1024];   // per-wave 2KB P slab (reused per ksl)
  const int tid = threadIdx.x;
  const int lane = tid & 63;
  const int w = tid >> 6;
  const int g = lane >> 4;
  const int qi = lane & 15;
  const int bid = (int)blockIdx.x;
  const int bh = bid & 31;          // low bits -> same bh on one XCD
  const int qt = (bid >> 5) & 15;
  const int s = bid >> 9;           // kv half
  const int b = bh >> 2, h = bh & 3;

  // Q fragments f=0,1 (B-operand of S^T): col q = f*16+qi, k(d) = half*32 + g*8 + j
  const size_t qrow0 = (size_t)b * 2048 + qt * 128 + w * 32 + qi;
  bf16x8 qf[2][2];
#pragma unroll
  for (int f = 0; f < 2; ++f) {
    const bf16* qp = qk + (qrow0 + f * 16) * 512 + h * 64 + g * 8;
    qf[f][0] = *(const bf16x8*)qp;
    qf[f][1] = *(const bf16x8*)(qp + 32);
  }

  float mrun[2] = {0.f, 0.f};
  float lsum[2] = {0.f, 0.f};
  f32x4 o[4][2];
#pragma unroll
  for (int i = 0; i < 4; ++i)
#pragma unroll
    for (int f = 0; f < 2; ++f) o[i][f] = (f32x4){0.f, 0.f, 0.f, 0.f};

  constexpr float THR = 8.0f / CEXP;

  // staging sources (frag-major pre-permute); this block's kv range = tiles [s*16, s*16+16)
  const char* kbase = (const char*)qk + ((size_t)b * 2048) * 1024 + 512 + h * 128 +
                      (size_t)s * 16 * 65536;
  const char* vbase = (const char*)vT + (size_t)bh * 262144 + (size_t)s * 16 * 128;
  const char* ks[2];
  const char* vs[2];
#pragma unroll
  for (int i = 0; i < 2; ++i) {
    const int fk = i * 2 + (w >> 1);
    const int half = w & 1;
    ks[i] = kbase + (fk * 16 + qi) * 1024 + half * 64 + g * 16;
    vs[i] = vbase + (size_t)(fk * 16 + qi) * 4096 + half * 64 + g * 16;
  }
  // P slab (2KB, private per wave)
  char* const pw = (char*)&Pl[w][0];
  int paddrb[2];
#pragma unroll
  for (int bb = 0; bb < 2; ++bb)
    paddrb[bb] = (bb * 2 + (g >> 1)) * 256 + qi * 16 + (g & 1) * 8;
  const char* const prd = pw + lane * 16;

  auto stage = [&](int slot) {
    char* kd = (char*)&Kl[0][0] + slot * 8192 + w * 1024;
    char* vd = (char*)&Vl[0][0] + slot * 8192 + w * 1024;
    gload16(ks[0], kd);
    gload16(ks[1], kd + 4096);
    gload16(vs[0], vd);
    gload16(vs[1], vd + 4096);
    ks[0] += 65536; ks[1] += 65536;
    vs[0] += 128;   vs[1] += 128;
  };

  stage(0);
  asm volatile("s_waitcnt vmcnt(0)" ::: "memory");
  __builtin_amdgcn_s_barrier();

  for (int t = 0; t < 16; ++t) {
    if (t < 15) stage((t + 1) & 1);   // issue early: latency hides under compute
    // ---- S^T = K·Q^T : linear frag reads ----
    const char* kb = (const char*)&Kl[0][0] + (t & 1) * 8192 + lane * 16;
    f32x4 st[4][2];
    __builtin_amdgcn_s_setprio(1);
#pragma unroll
    for (int fk = 0; fk < 4; ++fk) {
      const bf16x8 k0 = *(const bf16x8*)(kb + fk * 2048);
      const bf16x8 k1 = *(const bf16x8*)(kb + fk * 2048 + 1024);
#pragma unroll
      for (int f = 0; f < 2; ++f) {
        f32x4 z = (f32x4){0.f, 0.f, 0.f, 0.f};
        st[fk][f] = __builtin_amdgcn_mfma_f32_16x16x32_bf16(k0, qf[f][0], z, 0, 0, 0);
        st[fk][f] = __builtin_amdgcn_mfma_f32_16x16x32_bf16(k1, qf[f][1], st[fk][f], 0, 0, 0);
      }
    }
    __builtin_amdgcn_s_setprio(0);
    // ---- online softmax (lane-local col q = f*16+qi; kv slice = fk*16+g*4+j) ----
    float pmax[2];
#pragma unroll
    for (int f = 0; f < 2; ++f) {
      float m0 = fmaxf(fmaxf(st[0][f][0], st[0][f][1]), fmaxf(st[0][f][2], st[0][f][3]));
      float m1 = fmaxf(fmaxf(st[1][f][0], st[1][f][1]), fmaxf(st[1][f][2], st[1][f][3]));
      float m2 = fmaxf(fmaxf(st[2][f][0], st[2][f][1]), fmaxf(st[2][f][2], st[2][f][3]));
      float m3 = fmaxf(fmaxf(st[3][f][0], st[3][f][1]), fmaxf(st[3][f][2], st[3][f][3]));
      pmax[f] = fmaxf(fmaxf(m0, m1), fmaxf(m2, m3));
    }
    if (!__all(pmax[0] <= mrun[0] + THR && pmax[1] <= mrun[1] + THR)) {  // rare
#pragma unroll
      for (int f = 0; f < 2; ++f) {
        float mt = fmaxf(pmax[f], __shfl_xor(pmax[f], 16));
        mt = fmaxf(mt, __shfl_xor(mt, 32));
        const float mnew = fmaxf(mrun[f], mt);
        const float alpha = exp2f(CEXP * (mrun[f] - mnew));
        lsum[f] *= alpha;
#pragma unroll
        for (int fd = 0; fd < 4; ++fd)
#pragma unroll
          for (int j = 0; j < 4; ++j) o[fd][f][j] *= alpha;
        mrun[f] = mnew;
      }
    }
    unsigned pk[4][2][2];
#pragma unroll
    for (int f = 0; f < 2; ++f) {
      const float negcm = -CEXP * mrun[f];
      float ts = 0.f;
#pragma unroll
      for (int fk = 0; fk < 4; ++fk)
#pragma unroll
        for (int jp = 0; jp < 2; ++jp) {
          const float p0 = exp2f(fmaf(st[fk][f][2 * jp], CEXP, negcm));
          const float p1 = exp2f(fmaf(st[fk][f][2 * jp + 1], CEXP, negcm));
          ts += p0 + p1;
          union { bf16 h2[2]; unsigned u; } cv;
          cv.h2[0] = (bf16)p0;
          cv.h2[1] = (bf16)p1;
          pk[fk][f][jp] = cv.u;
        }
      lsum[f] += ts;
    }
    // ---- PV per ksl-half: P slab round-trip + V frag reads (all private/linear) ----
    const char* vb = (const char*)&Vl[0][0] + (t & 1) * 8192 + lane * 16;
#pragma unroll
    for (int ksl = 0; ksl < 2; ++ksl) {
#pragma unroll
      for (int bb = 0; bb < 2; ++bb) {
        const int fk = 2 * ksl + bb;
#pragma unroll
        for (int f = 0; f < 2; ++f) {
          u32x2 pv2;
          pv2[0] = pk[fk][f][0];
          pv2[1] = pk[fk][f][1];
          *(u32x2*)(pw + f * 1024 + paddrb[bb]) = pv2;
        }
      }
      bf16x8 pa[2];
#pragma unroll
      for (int f = 0; f < 2; ++f) pa[f] = *(const bf16x8*)(prd + f * 1024);
      __builtin_amdgcn_s_setprio(1);
#pragma unroll
      for (int fd = 0; fd < 4; ++fd) {
        const bf16x8 vv = *(const bf16x8*)(vb + fd * 2048 + ksl * 1024);
#pragma unroll
        for (int f = 0; f < 2; ++f)
          o[fd][f] = __builtin_amdgcn_mfma_f32_16x16x32_bf16(vv, pa[f], o[fd][f], 0, 0, 0);
      }
      __builtin_amdgcn_s_setprio(0);
    }
    asm volatile("s_waitcnt vmcnt(0)" ::: "memory");
    __builtin_amdgcn_s_barrier();
  }

  // ---- epilogue: reduce lsum across g-groups, write stats + unnormalized bf16 partials ----
#pragma unroll
  for (int f = 0; f < 2; ++f) {
    float l = lsum[f];
    l += __shfl_xor(l, 16);
    l += __shfl_xor(l, 32);
    lsum[f] = l;
  }
  if (g == 0) {
#pragma unroll
    for (int f = 0; f < 2; ++f) {
      float2 sv;
      sv.x = mrun[f];
      sv.y = lsum[f];
      *(float2*)(pstats + (((size_t)s * 32 + bh) * 2048 + qt * 128 + w * 32 + f * 16 + qi) * 2) = sv;
    }
  }
#pragma unroll
  for (int f = 0; f < 2; ++f) {
    bf16* const orow = po + ((size_t)s * 16384 + qrow0 + f * 16) * 256 + h * 64 + g * 4;
#pragma unroll
    for (int fd = 0; fd < 4; ++fd) {
      bf16x4 ov;
#pragma unroll
      for (int j = 0; j < 4; ++j) ov[j] = (bf16)o[fd][f][j];
      *(bf16x4*)(orow + fd * 16) = ov;
    }
  }
}

// ---------------- flash merge of the two kv-half partials ----------------------------------
__global__ __launch_bounds__(256) void attn_merge(const bf16* __restrict__ po,
                                                  const float* __restrict__ pstats,
                                                  bf16* __restrict__ ob) {
  const int idx = blockIdx.x * 256 + threadIdx.x;   // 16384*64
  const int r = idx >> 6;
  const int cq = (idx & 63) * 4;
  const int h = cq >> 6;
  const int bh = (r >> 11) * 4 + h;
  const int ql = r & 2047;
  const float2 s0 = *(const float2*)(pstats + (((size_t)bh) * 2048 + ql) * 2);
  const float2 s1 = *(const float2*)(pstats + (((size_t)32 + bh) * 2048 + ql) * 2);
  const float M = fmaxf(s0.x, s1.x);
  const float a0 = exp2f(CEXP * (s0.x - M));
  const float a1 = exp2f(CEXP * (s1.x - M));
  const float inv = 1.0f / (s0.y * a0 + s1.y * a1);
  const bf16x4 p0 = *(const bf16x4*)(po + (size_t)r * 256 + cq);
  const bf16x4 p1 = *(const bf16x4*)(po + ((size_t)16384 + r) * 256 + cq);
  bf16x4 ov;
#pragma unroll
  for (int j = 0; j < 4; ++j)
    ov[j] = (bf16)(((float)p0[j] * a0 + (float)p1[j] * a1) * inv);
  *(bf16x4*)(ob + (size_t)r * 256 + cq) = ov;
}

extern "C" void kernel_launch(void* const* d_in, const int* in_sizes, int n_in,
                              void* d_out, int out_size, void* d_ws, size_t ws_size,
                              hipStream_t stream) {
  const float* x      = (const float*)d_in[0];
  const float* qkv_w  = (const float*)d_in[1];
  const float* qkv_b  = (const float*)d_in[2];
  const float* proj_w = (const float*)d_in[3];
  const float* proj_b = (const float*)d_in[4];
  const float* ln1_g  = (const float*)d_in[5];
  const float* ln1_b  = (const float*)d_in[6];
  const float* ln2_g  = (const float*)d_in[7];
  const float* ln2_b  = (const float*)d_in[8];
  const float* mlp_w1 = (const float*)d_in[9];
  const float* mlp_b1 = (const float*)d_in[10];
  const float* mlp_w2 = (const float*)d_in[11];
  const float* mlp_b2 = (const float*)d_in[12];
  float* out = (float*)d_out;

  char* ws = (char*)d_ws;
  bf16* Wtqkv = (bf16*)(ws);              // [768][256]   393216 B
  bf16* WtP   = (bf16*)(ws + 393216);     // [256][256]   131072 B
  bf16* Wt1   = (bf16*)(ws + 524288);     // [512][256]   262144 B
  bf16* Wt2   = (bf16*)(ws + 786432);     // [256][512]   262144 B
  bf16* h     = (bf16*)(ws + 1048576);    // [16384][256] 8388608 B
  bf16* qkb   = (bf16*)(ws + 9437184);    // [16384][512] 16777216 B
  bf16* vT    = (bf16*)(ws + 26214400);   // [32][64][2048] 8388608 B
  bf16* obuf  = (bf16*)(ws + 34603008);   // [16384][256] 8388608 B
  float* x2   = (float*)(ws + 42991616);  // [16384][256] 16777216 B
  bf16* po    = (bf16*)(ws + 42991616);   // [2][16384][256] bf16 partials (dead before x2)
  float* pstats = (float*)(ws + 59768832);// [2][32][2048][2] f32  1 MB   (total 60.8 MB)
  bf16* a1 = qkb;  // reuse (qkb dead after attn)
  bf16* h2 = h;    // reuse (h dead after V gemm)

  wconv_all<<<2048, 256, 0, stream>>>(qkv_w, proj_w, mlp_w1, mlp_w2, Wtqkv, WtP, Wt1, Wt2);

  ln_fwd<<<4096, 256, 0, stream>>>(x, ln1_g, ln1_b, h);
  // Q,K: h @ W_qk  -> qkb [16384][512]
  gemm_bt<0><<<512, 256, 0, stream>>>(h, Wtqkv, qkv_b, nullptr, qkb, 16384, 512, 256);
  // V^T: Wv^T @ h^T -> vT [32][64][2048]  (swapped-operand GEMM, scatter epilogue)
  gemm_bt<1><<<256, 256, 0, stream>>>(Wtqkv + 512 * 256, h, qkv_b + 512, nullptr, vT, 256, 16384, 256);
  attn_fwd<<<1024, 256, 0, stream>>>(qkb, vT, po, pstats);
  attn_merge<<<4096, 256, 0, stream>>>(po, pstats, obuf);
  // proj + residual -> x2 (f32)
  gemm_bt<2><<<256, 256, 0, stream>>>(obuf, WtP, proj_b, x, x2, 16384, 256, 256);
  ln_fwd<<<4096, 256, 0, stream>>>(x2, ln2_g, ln2_b, h2);
  // fc1 + gelu -> a1 (bf16)
  gemm_bt<3><<<512, 256, 0, stream>>>(h2, Wt1, mlp_b1, nullptr, a1, 16384, 512, 256);
  // fc2 + residual -> out (f32)
  gemm_bt<2><<<256, 256, 0, stream>>>(a1, Wt2, mlp_b2, x2, out, 16384, 256, 512);
}